// Round 1
// baseline (789.794 us; speedup 1.0000x reference)
//
#include <hip/hip_runtime.h>

typedef unsigned int uint_t;
typedef unsigned short ushort_t;

using f32x4 = __attribute__((ext_vector_type(4))) float;
using bf16x8 = __attribute__((ext_vector_type(8))) short;

#define D_MODEL 2048
#define N_HEADS 16
#define N_KV    4
#define HD      128
#define KV_DIM  (N_KV * HD)          // 512
#define NQKV    (D_MODEL + 2*KV_DIM) // 3072
#define SEQ     2048
#define NB      4
#define MROWS   (NB * SEQ)           // 8192

__device__ __forceinline__ ushort_t f2bf(float f) {
    uint_t u = __float_as_uint(f);
    u = (u + 0x7FFFu + ((u >> 16) & 1u)) >> 16;   // RNE
    return (ushort_t)u;
}
__device__ __forceinline__ float bf2f(ushort_t h) {
    return __uint_as_float(((uint_t)h) << 16);
}

// ---------------------------------------------------------------- conv_x
__global__ __launch_bounds__(256) void conv_x_kernel(const float* __restrict__ in,
                                                     ushort_t* __restrict__ out, int n) {
    int i = (blockIdx.x * 256 + threadIdx.x) * 4;
    if (i >= n) return;
    float4 v = *(const float4*)&in[i];
    ushort_t o[4] = {f2bf(v.x), f2bf(v.y), f2bf(v.z), f2bf(v.w)};
    *(uint2*)&out[i] = *(uint2*)o;
}

// ------------------------------------------------------ transpose + cast
// W [K][Nout] fp32 -> WT [Nout][K] bf16
__global__ __launch_bounds__(256) void conv_wt_kernel(const float* __restrict__ W,
                                                      ushort_t* __restrict__ WT,
                                                      int K, int Nout) {
    __shared__ float tile[32][33];
    int n0 = blockIdx.x * 32, k0 = blockIdx.y * 32;
    int tx = threadIdx.x, ty = threadIdx.y;  // (32, 8)
    for (int i = 0; i < 4; ++i)
        tile[ty + 8*i][tx] = W[(size_t)(k0 + ty + 8*i) * Nout + n0 + tx];
    __syncthreads();
    for (int i = 0; i < 4; ++i)
        WT[(size_t)(n0 + ty + 8*i) * K + k0 + tx] = f2bf(tile[tx][ty + 8*i]);
}

// ------------------------------------------------------------------ GEMM
// C[M][N] = A[M][K] @ BT[N][K]^T + bias,  A/BT bf16 row-major, C bf16 or fp32.
// 128x128 block tile, BK=64, 4 waves in 2x2, each wave 64x64 via 4x4 MFMA tiles.
template <bool OUT_BF16>
__global__ __launch_bounds__(256) void gemm_bt_kernel(const ushort_t* __restrict__ A,
                                                      const ushort_t* __restrict__ BT,
                                                      const float* __restrict__ bias,
                                                      void* __restrict__ C,
                                                      int M, int N, int K) {
    __shared__ ushort_t As[128][72];   // +8 pad: 2-way-only LDS conflicts (free)
    __shared__ ushort_t Bs[128][72];
    const int bm = blockIdx.x * 128, bn = blockIdx.y * 128;
    const int t = threadIdx.x;
    const int w = t >> 6, lane = t & 63, quad = lane >> 4, r = lane & 15;
    const int mb = (w >> 1) * 64, nb = (w & 1) * 64;

    f32x4 acc[4][4] = {};

    for (int k0 = 0; k0 < K; k0 += 64) {
        // stage 128x64 of A and of BT: 1024 uint4 each, 4 per thread
        for (int i = 0; i < 4; ++i) {
            int idx = t + i * 256;          // uint4 index; 8 uint4 per 64-elem row
            int row = idx >> 3, cv = idx & 7;
            uint4 da = *(const uint4*)&A [(size_t)(bm + row) * K + k0 + cv * 8];
            *(uint4*)&As[row][cv * 8] = da;
            uint4 db = *(const uint4*)&BT[(size_t)(bn + row) * K + k0 + cv * 8];
            *(uint4*)&Bs[row][cv * 8] = db;
        }
        __syncthreads();
        for (int kk = 0; kk < 64; kk += 32) {
            bf16x8 af[4], bf[4];
            for (int i = 0; i < 4; ++i)
                af[i] = *(const bf16x8*)&As[mb + i * 16 + r][kk + quad * 8];
            for (int j = 0; j < 4; ++j)
                bf[j] = *(const bf16x8*)&Bs[nb + j * 16 + r][kk + quad * 8];
            for (int i = 0; i < 4; ++i)
                for (int j = 0; j < 4; ++j)
                    acc[i][j] = __builtin_amdgcn_mfma_f32_16x16x32_bf16(af[i], bf[j], acc[i][j], 0, 0, 0);
        }
        __syncthreads();
    }
    // epilogue: C/D layout col=lane&15, row=quad*4+reg
    for (int i = 0; i < 4; ++i)
        for (int j = 0; j < 4; ++j)
            for (int reg = 0; reg < 4; ++reg) {
                int row = bm + mb + i * 16 + quad * 4 + reg;
                int col = bn + nb + j * 16 + r;
                float v = acc[i][j][reg] + bias[col];
                if (OUT_BF16) ((ushort_t*)C)[(size_t)row * N + col] = f2bf(v);
                else          ((float*)C)[(size_t)row * N + col] = v;
            }
}

// -------------------------------------------- RMSNorm + GQA rearrangement
// qkv bf16 [8192][3072] -> Q [NB][16][SEQ][128], K/V [NB][4][SEQ][128] bf16
__global__ __launch_bounds__(256) void rms_rearrange_kernel(const ushort_t* __restrict__ qkv,
                                                            const float* __restrict__ q_scale,
                                                            const float* __restrict__ k_scale,
                                                            ushort_t* __restrict__ Q,
                                                            ushort_t* __restrict__ Kb,
                                                            ushort_t* __restrict__ Vb) {
    int rid = blockIdx.x;                 // n*SEQ + l
    int n = rid >> 11, l = rid & 2047;
    int w = threadIdx.x >> 6, lane = threadIdx.x & 63;
    const ushort_t* rowp = qkv + (size_t)rid * NQKV;
    int d0 = lane * 2;
    for (int g = w; g < 24; g += 4) {     // 24 head-groups of 128
        uint_t pair = *(const uint_t*)&rowp[g * 128 + d0];
        float v0 = bf2f((ushort_t)(pair & 0xffff));
        float v1 = bf2f((ushort_t)(pair >> 16));
        if (g < 20) {                      // q or k: rmsnorm over the 128 group
            float ss = v0 * v0 + v1 * v1;
            for (int m = 1; m < 64; m <<= 1) ss += __shfl_xor(ss, m);
            float inv = rsqrtf(ss * (1.0f / 128.0f) + 1e-6f);
            const float* sc = (g < 16) ? q_scale : k_scale;
            v0 *= inv * sc[d0];
            v1 *= inv * sc[d0 + 1];
        }
        uint_t op = (uint_t)f2bf(v0) | ((uint_t)f2bf(v1) << 16);
        ushort_t* base;
        size_t dst;
        if (g < 16)      { base = Q;  dst = (((size_t)(n * 16 + g) * SEQ + l) * HD + d0); }
        else if (g < 20) { base = Kb; dst = (((size_t)(n * 4 + (g - 16)) * SEQ + l) * HD + d0); }
        else             { base = Vb; dst = (((size_t)(n * 4 + (g - 20)) * SEQ + l) * HD + d0); }
        *(uint_t*)&base[dst] = op;
    }
}

// --------------------------------------------------- flash causal attention
// grid (qt=32, h=16, n=4), block 256 (4 waves). 64-row Q tile, 64-col KV tiles.
__global__ __launch_bounds__(256) void attn_kernel(const ushort_t* __restrict__ Q,
                                                   const ushort_t* __restrict__ K,
                                                   const ushort_t* __restrict__ V,
                                                   ushort_t* __restrict__ Y) {
    const int qt = blockIdx.x, h = blockIdx.y, n = blockIdx.z;
    const int kvh = h >> 2;  // repeat_interleave: head h uses kv head h/4
    const ushort_t* Qp = Q + (size_t)(n * N_HEADS + h) * SEQ * HD;
    const ushort_t* Kp = K + (size_t)(n * N_KV + kvh) * SEQ * HD;
    const ushort_t* Vp = V + (size_t)(n * N_KV + kvh) * SEQ * HD;

    __shared__ ushort_t Qs[64][136];
    __shared__ ushort_t Ks[64][136];
    __shared__ ushort_t Vts[128][72];   // V transposed [d][key], key XOR-swizzled
    __shared__ ushort_t Ps[64][72];

    const int t = threadIdx.x, w = t >> 6, lane = t & 63, quad = lane >> 4, r = lane & 15;

    // stage Q tile (64x128)
    for (int i = 0; i < 4; ++i) {
        int idx = t + i * 256;          // 16 uint4 per row
        int row = idx >> 4, cv = idx & 15;
        uint4 d = *(const uint4*)&Qp[(size_t)(qt * 64 + row) * HD + cv * 8];
        *(uint4*)&Qs[row][cv * 8] = d;
    }

    f32x4 oacc[8] = {};
    float m_i[4], l_i[4];
    for (int reg = 0; reg < 4; ++reg) { m_i[reg] = -1e30f; l_i[reg] = 0.f; }
    const float scale = 0.08838834764831845f;   // 1/sqrt(128)

    for (int ct = 0; ct <= qt; ++ct) {
        __syncthreads();
        // stage K tile + transposed-swizzled V tile
        for (int i = 0; i < 4; ++i) {
            int idx = t + i * 256;
            int row = idx >> 4, cv = idx & 15;    // row = key idx, cv*8 = d0
            uint4 dk = *(const uint4*)&Kp[(size_t)(ct * 64 + row) * HD + cv * 8];
            *(uint4*)&Ks[row][cv * 8] = dk;
            uint4 dv = *(const uint4*)&Vp[(size_t)(ct * 64 + row) * HD + cv * 8];
            const ushort_t* vv = (const ushort_t*)&dv;
            int d0 = cv * 8;
            int keysw = row ^ ((cv & 7) << 3);    // (d>>3)&7 == cv&7 for all 8 elems
            for (int j = 0; j < 8; ++j) Vts[d0 + j][keysw] = vv[j];
        }
        __syncthreads();

        // S strip [16 x 64] for wave w: QK^T
        f32x4 sacc[4] = {};
        for (int kk = 0; kk < HD; kk += 32) {
            bf16x8 aq = *(const bf16x8*)&Qs[w * 16 + r][kk + quad * 8];
            for (int jt = 0; jt < 4; ++jt) {
                bf16x8 bk = *(const bf16x8*)&Ks[jt * 16 + r][kk + quad * 8];
                sacc[jt] = __builtin_amdgcn_mfma_f32_16x16x32_bf16(aq, bk, sacc[jt], 0, 0, 0);
            }
        }

        // online softmax (C-layout: row = quad*4+reg, col = jt*16 + r)
        float alpha[4];
        for (int reg = 0; reg < 4; ++reg) {
            int qrow = qt * 64 + w * 16 + quad * 4 + reg;
            float sv[4];
            float mx = m_i[reg];
            for (int jt = 0; jt < 4; ++jt) {
                float s = sacc[jt][reg] * scale;
                int kcol = ct * 64 + jt * 16 + r;
                if (kcol > qrow) s = -1e30f;       // causal
                sv[jt] = s;
                mx = fmaxf(mx, s);
            }
            for (int msk = 1; msk < 16; msk <<= 1) mx = fmaxf(mx, __shfl_xor(mx, msk));
            alpha[reg] = __expf(m_i[reg] - mx);
            float rowsum = 0.f;
            for (int jt = 0; jt < 4; ++jt) {
                float p = __expf(sv[jt] - mx);
                ushort_t pb = f2bf(p);
                rowsum += bf2f(pb);                // sum the ROUNDED p: exact normalization
                Ps[w * 16 + quad * 4 + reg][jt * 16 + r] = pb;
            }
            for (int msk = 1; msk < 16; msk <<= 1) rowsum += __shfl_xor(rowsum, msk);
            l_i[reg] = l_i[reg] * alpha[reg] + rowsum;
            m_i[reg] = mx;
        }
        for (int dt = 0; dt < 8; ++dt)
            for (int reg = 0; reg < 4; ++reg) oacc[dt][reg] *= alpha[reg];

        // PV: O[16x128] += P[16x64] @ V[64x128]  (wave-private Ps rows: no barrier)
        for (int kk = 0; kk < 64; kk += 32) {
            bf16x8 pa = *(const bf16x8*)&Ps[w * 16 + r][kk + quad * 8];
            for (int dt = 0; dt < 8; ++dt) {
                int d = dt * 16 + r;
                int kb = (kk + quad * 8) ^ (((d >> 3) & 7) << 3);
                bf16x8 bv = *(const bf16x8*)&Vts[d][kb];
                oacc[dt] = __builtin_amdgcn_mfma_f32_16x16x32_bf16(pa, bv, oacc[dt], 0, 0, 0);
            }
        }
    }

    // epilogue: Y[n][l][h*128+d] bf16
    for (int reg = 0; reg < 4; ++reg) {
        float invl = 1.0f / l_i[reg];
        int lrow = qt * 64 + w * 16 + quad * 4 + reg;
        size_t base = ((size_t)(n * SEQ + lrow)) * D_MODEL + h * HD;
        for (int dt = 0; dt < 8; ++dt)
            Y[base + dt * 16 + r] = f2bf(oacc[dt][reg] * invl);
    }
}

// ------------------------------------------------------------------ launch
extern "C" void kernel_launch(void* const* d_in, const int* in_sizes, int n_in,
                              void* d_out, int out_size, void* d_ws, size_t ws_size,
                              hipStream_t stream) {
    const float* x       = (const float*)d_in[0];
    const float* Wqkv    = (const float*)d_in[1];
    const float* bqkv    = (const float*)d_in[2];
    const float* q_scale = (const float*)d_in[3];
    const float* k_scale = (const float*)d_in[4];
    const float* Wout    = (const float*)d_in[5];
    const float* bout    = (const float*)d_in[6];
    float* out = (float*)d_out;

    // workspace layout (bf16 elements); xb doubles as y after QKV GEMM,
    // WT doubles as Wout^T after QKV GEMM.
    ushort_t* xb  = (ushort_t*)d_ws;                    // 8192*2048
    ushort_t* WT  = xb  + (size_t)MROWS * D_MODEL;      // 3072*2048
    ushort_t* qkv = WT  + (size_t)NQKV * D_MODEL;       // 8192*3072
    ushort_t* Qb  = qkv + (size_t)MROWS * NQKV;         // 4*16*2048*128
    ushort_t* Kb  = Qb  + (size_t)NB * N_HEADS * SEQ * HD;  // 4*4*2048*128
    ushort_t* Vb  = Kb  + (size_t)NB * N_KV * SEQ * HD;

    // 1. x -> bf16
    conv_x_kernel<<<MROWS * D_MODEL / 1024, 256, 0, stream>>>(x, xb, MROWS * D_MODEL);
    // 2. Wqkv -> Wqkv^T bf16
    conv_wt_kernel<<<dim3(NQKV / 32, D_MODEL / 32), dim3(32, 8), 0, stream>>>(Wqkv, WT, D_MODEL, NQKV);
    // 3. qkv = x @ Wqkv + bqkv   (bf16 out)
    gemm_bt_kernel<true><<<dim3(MROWS / 128, NQKV / 128), 256, 0, stream>>>(xb, WT, bqkv, qkv, MROWS, NQKV, D_MODEL);
    // 4. rmsnorm + rearrange
    rms_rearrange_kernel<<<MROWS, 256, 0, stream>>>(qkv, q_scale, k_scale, Qb, Kb, Vb);
    // 5. Wout -> Wout^T bf16 (reuse WT region)
    conv_wt_kernel<<<dim3(D_MODEL / 32, D_MODEL / 32), dim3(32, 8), 0, stream>>>(Wout, WT, D_MODEL, D_MODEL);
    // 6. attention -> y (reuse xb region)
    attn_kernel<<<dim3(SEQ / 64, N_HEADS, NB), 256, 0, stream>>>(Qb, Kb, Vb, xb);
    // 7. out = y @ Wout + bout   (fp32 out)
    gemm_bt_kernel<false><<<dim3(MROWS / 128, D_MODEL / 128), 256, 0, stream>>>(xb, WT, bout, out, MROWS, D_MODEL, D_MODEL);
}

// Round 2
// 500.674 us; speedup vs baseline: 1.5775x; 1.5775x over previous
//
#include <hip/hip_runtime.h>

typedef unsigned int uint_t;
typedef unsigned short ushort_t;

using f32x4 = __attribute__((ext_vector_type(4))) float;
using bf16x8 = __attribute__((ext_vector_type(8))) short;

#define D_MODEL 2048
#define N_HEADS 16
#define N_KV    4
#define HD      128
#define KV_DIM  (N_KV * HD)          // 512
#define NQKV    (D_MODEL + 2*KV_DIM) // 3072
#define SEQ     2048
#define NB      4
#define MROWS   (NB * SEQ)           // 8192
#define SM_SCALE 0.08838834764831845f  // 1/sqrt(128)

__device__ __forceinline__ ushort_t f2bf(float f) {
    uint_t u = __float_as_uint(f);
    u = (u + 0x7FFFu + ((u >> 16) & 1u)) >> 16;   // RNE
    return (ushort_t)u;
}
__device__ __forceinline__ float bf2f(ushort_t h) {
    return __uint_as_float(((uint_t)h) << 16);
}

// async global->LDS, 16 B/lane, lands at (wave-uniform lds base) + lane*16
__device__ __forceinline__ void gload16(const ushort_t* g, ushort_t* l) {
    __builtin_amdgcn_global_load_lds(
        (const __attribute__((address_space(1))) unsigned int*)g,
        (__attribute__((address_space(3))) unsigned int*)l, 16, 0, 0);
}

// ---------------------------------------------------------------- conv_x
__global__ __launch_bounds__(256) void conv_x_kernel(const float* __restrict__ in,
                                                     ushort_t* __restrict__ out, int n) {
    int i = (blockIdx.x * 256 + threadIdx.x) * 4;
    if (i >= n) return;
    float4 v = *(const float4*)&in[i];
    ushort_t o[4] = {f2bf(v.x), f2bf(v.y), f2bf(v.z), f2bf(v.w)};
    *(uint2*)&out[i] = *(uint2*)o;
}

// ------------------------------------------------------ transpose + cast
// W [K][Nout] fp32 -> WT [Nout][K] bf16
__global__ __launch_bounds__(256) void conv_wt_kernel(const float* __restrict__ W,
                                                      ushort_t* __restrict__ WT,
                                                      int K, int Nout) {
    __shared__ float tile[32][33];
    int n0 = blockIdx.x * 32, k0 = blockIdx.y * 32;
    int tx = threadIdx.x, ty = threadIdx.y;  // (32, 8)
    for (int i = 0; i < 4; ++i)
        tile[ty + 8*i][tx] = W[(size_t)(k0 + ty + 8*i) * Nout + n0 + tx];
    __syncthreads();
    for (int i = 0; i < 4; ++i)
        WT[(size_t)(n0 + ty + 8*i) * K + k0 + tx] = f2bf(tile[tx][ty + 8*i]);
}

// --------------------------------------------------------------- vt_kernel
// qkv [8192][3072] cols [2560..3072) -> Vt [n*4+kvh][d (128)][l (2048)] bf16
__global__ __launch_bounds__(256) void vt_kernel(const ushort_t* __restrict__ qkv,
                                                 ushort_t* __restrict__ Vt) {
    __shared__ ushort_t tile[64][72];
    int l0 = blockIdx.x * 64, d0 = blockIdx.y * 64;
    int nk = blockIdx.z;                 // n*4 + kvh
    int n = nk >> 2, kvh = nk & 3;
    int t = threadIdx.x;
    const int coff = 2560 + kvh * 128 + d0;
    for (int i = 0; i < 2; ++i) {
        int idx = t + i * 256;           // 512 uint4 chunks
        int rr = idx >> 3, c = idx & 7;
        uint4 v = *(const uint4*)&qkv[(size_t)(n * SEQ + l0 + rr) * NQKV + coff + c * 8];
        *(uint4*)&tile[rr][c * 8] = v;
    }
    __syncthreads();
    for (int i = 0; i < 2; ++i) {
        int idx = t + i * 256;
        int dr = idx >> 3, c2 = idx & 7;
        ushort_t o[8];
        for (int j = 0; j < 8; ++j) o[j] = tile[c2 * 8 + j][dr];
        *(uint4*)&Vt[((size_t)nk * HD + d0 + dr) * SEQ + l0 + c2 * 8] = *(uint4*)o;
    }
}

// ------------------------------------------------------------------ GEMM
// C[M][N] = A[M][K] @ BT[N][K]^T + bias.  global_load_lds staging, BK=64.
// LDS 16B chunks XOR-swizzled: slot (row,c) holds global chunk c^(row&7).
template <bool OUT_BF16>
__global__ __launch_bounds__(256) void gemm_bt_kernel(const ushort_t* __restrict__ A,
                                                      const ushort_t* __restrict__ BT,
                                                      const float* __restrict__ bias,
                                                      void* __restrict__ C,
                                                      int M, int N, int K) {
    __shared__ ushort_t As[128][64];
    __shared__ ushort_t Bs[128][64];
    const int bm = blockIdx.x * 128, bn = blockIdx.y * 128;
    const int t = threadIdx.x;
    const int w = t >> 6, lane = t & 63, quad = lane >> 4, r = lane & 15;
    const int mb = (w >> 1) * 64, nb = (w & 1) * 64;

    f32x4 acc[4][4] = {};

    for (int k0 = 0; k0 < K; k0 += 64) {
        for (int i = 0; i < 4; ++i) {
            int ci = (w * 4 + i) * 64 + lane;         // chunk 0..1023
            int row = ci >> 3, c = ci & 7, cg = c ^ (row & 7);
            gload16(&A [(size_t)(bm + row) * K + k0 + cg * 8], &As[0][0] + (w * 4 + i) * 512);
            gload16(&BT[(size_t)(bn + row) * K + k0 + cg * 8], &Bs[0][0] + (w * 4 + i) * 512);
        }
        __syncthreads();
        for (int kk = 0; kk < 64; kk += 32) {
            bf16x8 af[4], bfr[4];
            int k4 = kk >> 3;                          // 0 or 4
            for (int i = 0; i < 4; ++i)
                af[i]  = *(const bf16x8*)&As[mb + i * 16 + r][((k4 + quad) ^ (r & 7)) * 8];
            for (int j = 0; j < 4; ++j)
                bfr[j] = *(const bf16x8*)&Bs[nb + j * 16 + r][((k4 + quad) ^ (r & 7)) * 8];
            for (int i = 0; i < 4; ++i)
                for (int j = 0; j < 4; ++j)
                    acc[i][j] = __builtin_amdgcn_mfma_f32_16x16x32_bf16(af[i], bfr[j], acc[i][j], 0, 0, 0);
        }
        __syncthreads();
    }
    for (int i = 0; i < 4; ++i)
        for (int j = 0; j < 4; ++j)
            for (int reg = 0; reg < 4; ++reg) {
                int row = bm + mb + i * 16 + quad * 4 + reg;
                int col = bn + nb + j * 16 + r;
                float v = acc[i][j][reg] + bias[col];
                if (OUT_BF16) ((ushort_t*)C)[(size_t)row * N + col] = f2bf(v);
                else          ((float*)C)[(size_t)row * N + col] = v;
            }
}

// -------------------------------------------- RMSNorm + GQA rearrangement
// qkv bf16 [8192][3072] -> Q [NB][16][SEQ][128] (softmax scale folded),
//                          K [NB][4][SEQ][128]
__global__ __launch_bounds__(256) void rms_rearrange_kernel(const ushort_t* __restrict__ qkv,
                                                            const float* __restrict__ q_scale,
                                                            const float* __restrict__ k_scale,
                                                            ushort_t* __restrict__ Q,
                                                            ushort_t* __restrict__ Kb) {
    int rid = blockIdx.x;                 // n*SEQ + l
    int n = rid >> 11, l = rid & 2047;
    int w = threadIdx.x >> 6, lane = threadIdx.x & 63;
    const ushort_t* rowp = qkv + (size_t)rid * NQKV;
    int d0 = lane * 2;
    for (int g = w; g < 20; g += 4) {     // q (16) + k (4) head-groups of 128
        uint_t pair = *(const uint_t*)&rowp[g * 128 + d0];
        float v0 = bf2f((ushort_t)(pair & 0xffff));
        float v1 = bf2f((ushort_t)(pair >> 16));
        float ss = v0 * v0 + v1 * v1;
        for (int m = 1; m < 64; m <<= 1) ss += __shfl_xor(ss, m);
        float inv = rsqrtf(ss * (1.0f / 128.0f) + 1e-6f);
        ushort_t* base;
        size_t dst;
        if (g < 16) {
            inv *= SM_SCALE;               // fold softmax scale into Q
            v0 *= inv * q_scale[d0];
            v1 *= inv * q_scale[d0 + 1];
            base = Q;  dst = (((size_t)(n * 16 + g) * SEQ + l) * HD + d0);
        } else {
            v0 *= inv * k_scale[d0];
            v1 *= inv * k_scale[d0 + 1];
            base = Kb; dst = (((size_t)(n * 4 + (g - 16)) * SEQ + l) * HD + d0);
        }
        uint_t op = (uint_t)f2bf(v0) | ((uint_t)f2bf(v1) << 16);
        *(uint_t*)&base[dst] = op;
    }
}

// --------------------------------------------------- flash causal attention
// grid (16, 16, 4) = 1024 blocks = exactly 4/CU (LDS 40960 -> 4 blocks/CU).
// Each block does paired q-tiles {pid, 31-pid}: 33 tile-steps, perfectly balanced.
// Fixed-max softmax (RMSnormed q,k bound s <= 11.32 -> exp safe in fp32).
__global__ __launch_bounds__(256, 4) void attn_kernel(const ushort_t* __restrict__ Q,
                                                      const ushort_t* __restrict__ K,
                                                      const ushort_t* __restrict__ Vt,
                                                      ushort_t* __restrict__ Y) {
    const int pid = blockIdx.x, h = blockIdx.y, n = blockIdx.z;
    const int kvh = h >> 2;
    const ushort_t* Qp = Q  + (size_t)(n * N_HEADS + h) * SEQ * HD;
    const ushort_t* Kp = K  + (size_t)(n * N_KV + kvh) * SEQ * HD;
    const ushort_t* Vp = Vt + (size_t)(n * N_KV + kvh) * HD * SEQ;   // [d][l]

    __shared__ ushort_t Ks[64][128];    // 16 KB, chunk-swizzled
    __shared__ ushort_t Vts[128][64];   // 16 KB, chunk-swizzled ([d][key])
    __shared__ ushort_t Ps[64][64];     // 8 KB, 16-col swizzle by (row>>2)&3

    const int t = threadIdx.x, w = t >> 6, lane = t & 63, quad = lane >> 4, r = lane & 15;

    for (int rep = 0; rep < 2; ++rep) {
        const int qt = rep ? (31 - pid) : pid;
        __syncthreads();
        // stage Q tile (64x128) into Ks buffer
        for (int i = 0; i < 4; ++i) {
            int ci = (w * 4 + i) * 64 + lane;         // chunk 0..1023, 16 chunks/row
            int row = ci >> 4, c = ci & 15, cg = c ^ (row & 7);
            gload16(&Qp[(size_t)(qt * 64 + row) * HD + cg * 8], &Ks[0][0] + (w * 4 + i) * 512);
        }
        __syncthreads();
        bf16x8 aq[4];
        for (int kc = 0; kc < 4; ++kc)
            aq[kc] = *(const bf16x8*)&Ks[w * 16 + r][((kc * 4 + quad) ^ (r & 7)) * 8];

        f32x4 oacc[8] = {};
        float lsum[4] = {0.f, 0.f, 0.f, 0.f};

        for (int ct = 0; ct <= qt; ++ct) {
            __syncthreads();    // all waves done reading Ks/Vts from previous step
            for (int i = 0; i < 4; ++i) {
                int ci = (w * 4 + i) * 64 + lane;
                {   // K tile 64x128: 16 chunks/row
                    int row = ci >> 4, c = ci & 15, cg = c ^ (row & 7);
                    gload16(&Kp[(size_t)(ct * 64 + row) * HD + cg * 8], &Ks[0][0] + (w * 4 + i) * 512);
                }
                {   // Vt tile 128x64: 8 chunks/row
                    int row = ci >> 3, c = ci & 7, cg = c ^ (row & 7);
                    gload16(&Vp[(size_t)row * SEQ + ct * 64 + cg * 8], &Vts[0][0] + (w * 4 + i) * 512);
                }
            }
            __syncthreads();

            // S strip [16 x 64]: QK^T (scale already folded into Q)
            f32x4 sacc[4] = {};
            for (int kc = 0; kc < 4; ++kc)
                for (int jt = 0; jt < 4; ++jt) {
                    bf16x8 bk = *(const bf16x8*)&Ks[jt * 16 + r][((kc * 4 + quad) ^ (r & 7)) * 8];
                    sacc[jt] = __builtin_amdgcn_mfma_f32_16x16x32_bf16(aq[kc], bk, sacc[jt], 0, 0, 0);
                }

            // fixed-max softmax, P -> LDS (bf16)
            const bool diag = (ct == qt);
            for (int reg = 0; reg < 4; ++reg) {
                int prow = w * 16 + quad * 4 + reg;         // Ps row
                int qrow = prow;                            // local q row (tiles aligned)
                float rsum = 0.f;
                for (int jt = 0; jt < 4; ++jt) {
                    float s = sacc[jt][reg];
                    if (diag && (jt * 16 + r) > qrow) s = -1e30f;
                    float p = __expf(s);
                    ushort_t pb = f2bf(p);
                    rsum += bf2f(pb);                       // sum rounded p: exact normalization
                    Ps[prow][(jt * 16 + r) ^ (quad << 4)] = pb;
                }
                lsum[reg] += rsum;
            }

            // PV: O[16x128] += P[16x64] @ V[64x128] (wave-private Ps rows)
            for (int kk = 0; kk < 64; kk += 32) {
                int prow = w * 16 + r;
                bf16x8 pa = *(const bf16x8*)&Ps[prow][(kk + quad * 8) ^ ((((r >> 2) & 3)) << 4)];
                for (int dt = 0; dt < 8; ++dt) {
                    bf16x8 bv = *(const bf16x8*)&Vts[dt * 16 + r][(((kk >> 3) + quad) ^ (r & 7)) * 8];
                    oacc[dt] = __builtin_amdgcn_mfma_f32_16x16x32_bf16(pa, bv, oacc[dt], 0, 0, 0);
                }
            }
        }

        // epilogue: single end-of-loop row-sum reduction, then Y
        for (int reg = 0; reg < 4; ++reg) {
            float s = lsum[reg];
            for (int m = 1; m < 16; m <<= 1) s += __shfl_xor(s, m);
            float invl = 1.0f / s;
            int lrow = qt * 64 + w * 16 + quad * 4 + reg;
            size_t base = ((size_t)(n * SEQ + lrow)) * D_MODEL + h * HD;
            for (int dt = 0; dt < 8; ++dt)
                Y[base + dt * 16 + r] = f2bf(oacc[dt][reg] * invl);
        }
    }
}

// ------------------------------------------------------------------ launch
extern "C" void kernel_launch(void* const* d_in, const int* in_sizes, int n_in,
                              void* d_out, int out_size, void* d_ws, size_t ws_size,
                              hipStream_t stream) {
    const float* x       = (const float*)d_in[0];
    const float* Wqkv    = (const float*)d_in[1];
    const float* bqkv    = (const float*)d_in[2];
    const float* q_scale = (const float*)d_in[3];
    const float* k_scale = (const float*)d_in[4];
    const float* Wout    = (const float*)d_in[5];
    const float* bout    = (const float*)d_in[6];
    float* out = (float*)d_out;

    ushort_t* xb  = (ushort_t*)d_ws;                    // 8192*2048 (later: y)
    ushort_t* WT  = xb  + (size_t)MROWS * D_MODEL;      // 3072*2048 (later: WoutT)
    ushort_t* qkv = WT  + (size_t)NQKV * D_MODEL;       // 8192*3072
    ushort_t* Qb  = qkv + (size_t)MROWS * NQKV;         // 4*16*2048*128
    ushort_t* Kb  = Qb  + (size_t)NB * N_HEADS * SEQ * HD;  // 4*4*2048*128
    ushort_t* Vtb = Kb  + (size_t)NB * N_KV * SEQ * HD;     // 4*4*128*2048

    conv_x_kernel<<<MROWS * D_MODEL / 1024, 256, 0, stream>>>(x, xb, MROWS * D_MODEL);
    conv_wt_kernel<<<dim3(NQKV / 32, D_MODEL / 32), dim3(32, 8), 0, stream>>>(Wqkv, WT, D_MODEL, NQKV);
    gemm_bt_kernel<true><<<dim3(MROWS / 128, NQKV / 128), 256, 0, stream>>>(xb, WT, bqkv, qkv, MROWS, NQKV, D_MODEL);
    rms_rearrange_kernel<<<MROWS, 256, 0, stream>>>(qkv, q_scale, k_scale, Qb, Kb);
    vt_kernel<<<dim3(SEQ / 64, HD / 64, NB * N_KV), 256, 0, stream>>>(qkv, Vtb);
    conv_wt_kernel<<<dim3(D_MODEL / 32, D_MODEL / 32), dim3(32, 8), 0, stream>>>(Wout, WT, D_MODEL, D_MODEL);
    attn_kernel<<<dim3(16, N_HEADS, NB), 256, 0, stream>>>(Qb, Kb, Vtb, xb);
    gemm_bt_kernel<false><<<dim3(MROWS / 128, D_MODEL / 128), 256, 0, stream>>>(xb, WT, bout, out, MROWS, D_MODEL, D_MODEL);
}

// Round 3
// 474.924 us; speedup vs baseline: 1.6630x; 1.0542x over previous
//
#include <hip/hip_runtime.h>

typedef unsigned int uint_t;
typedef unsigned short ushort_t;

using f32x4 = __attribute__((ext_vector_type(4))) float;
using bf16x8 = __attribute__((ext_vector_type(8))) short;

#define D_MODEL 2048
#define N_HEADS 16
#define N_KV    4
#define HD      128
#define KV_DIM  (N_KV * HD)          // 512
#define NQKV    (D_MODEL + 2*KV_DIM) // 3072
#define SEQ     2048
#define NB      4
#define MROWS   (NB * SEQ)           // 8192
#define SM_SCALE 0.08838834764831845f  // 1/sqrt(128)

__device__ __forceinline__ ushort_t f2bf(float f) {
    uint_t u = __float_as_uint(f);
    u = (u + 0x7FFFu + ((u >> 16) & 1u)) >> 16;   // RNE
    return (ushort_t)u;
}

// async global->LDS, 16 B/lane, lands at (wave-uniform lds base) + lane*16
__device__ __forceinline__ void gload16(const ushort_t* g, ushort_t* l) {
    __builtin_amdgcn_global_load_lds(
        (const __attribute__((address_space(1))) unsigned int*)g,
        (__attribute__((address_space(3))) unsigned int*)l, 16, 0, 0);
}

// ---------------------------------------------------------------- conv_x
__global__ __launch_bounds__(256) void conv_x_kernel(const float* __restrict__ in,
                                                     ushort_t* __restrict__ out, int n) {
    int i = (blockIdx.x * 256 + threadIdx.x) * 4;
    if (i >= n) return;
    float4 v = *(const float4*)&in[i];
    ushort_t o[4] = {f2bf(v.x), f2bf(v.y), f2bf(v.z), f2bf(v.w)};
    *(uint2*)&out[i] = *(uint2*)o;
}

// ------------------------------------------------------ transpose + cast
// W [K][Nout] fp32 -> WT [Nout][K] bf16
__global__ __launch_bounds__(256) void conv_wt_kernel(const float* __restrict__ W,
                                                      ushort_t* __restrict__ WT,
                                                      int K, int Nout) {
    __shared__ float tile[32][33];
    int n0 = blockIdx.x * 32, k0 = blockIdx.y * 32;
    int tx = threadIdx.x, ty = threadIdx.y;  // (32, 8)
    for (int i = 0; i < 4; ++i)
        tile[ty + 8*i][tx] = W[(size_t)(k0 + ty + 8*i) * Nout + n0 + tx];
    __syncthreads();
    for (int i = 0; i < 4; ++i)
        WT[(size_t)(n0 + ty + 8*i) * K + k0 + tx] = f2bf(tile[tx][ty + 8*i]);
}

// --------------------------------------------------------------- vt_kernel
// Vn [nk][l (2048)][d (128)] bf16 -> Vt [nk][d (128)][l (2048)] bf16
__global__ __launch_bounds__(256) void vt_kernel(const ushort_t* __restrict__ Vn,
                                                 ushort_t* __restrict__ Vt) {
    __shared__ ushort_t tile[64][72];
    int l0 = blockIdx.x * 64, d0 = blockIdx.y * 64;
    int nk = blockIdx.z;                 // n*4 + kvh
    int t = threadIdx.x;
    for (int i = 0; i < 2; ++i) {
        int idx = t + i * 256;           // 512 uint4 chunks
        int rr = idx >> 3, c = idx & 7;
        uint4 v = *(const uint4*)&Vn[((size_t)nk * SEQ + l0 + rr) * HD + d0 + c * 8];
        *(uint4*)&tile[rr][c * 8] = v;
    }
    __syncthreads();
    for (int i = 0; i < 2; ++i) {
        int idx = t + i * 256;
        int dr = idx >> 3, c2 = idx & 7;
        ushort_t o[8];
        for (int j = 0; j < 8; ++j) o[j] = tile[c2 * 8 + j][dr];
        *(uint4*)&Vt[((size_t)nk * HD + d0 + dr) * SEQ + l0 + c2 * 8] = *(uint4*)o;
    }
}

// ------------------------------------------------- GEMM main-loop (shared)
#define GEMM_MAIN_LOOP(A, BT, K)                                                   \
    for (int k0 = 0; k0 < K; k0 += 64) {                                           \
        for (int i = 0; i < 4; ++i) {                                              \
            int ci = (w * 4 + i) * 64 + lane;                                      \
            int row = ci >> 3, c = ci & 7, cg = c ^ (row & 7);                     \
            gload16(&A [(size_t)(bm + row) * K + k0 + cg * 8], &As[0][0] + (w * 4 + i) * 512); \
            gload16(&BT[(size_t)(bn + row) * K + k0 + cg * 8], &Bs[0][0] + (w * 4 + i) * 512); \
        }                                                                          \
        __syncthreads();                                                           \
        for (int kk = 0; kk < 64; kk += 32) {                                      \
            bf16x8 af[4], bfr[4];                                                  \
            int k4 = kk >> 3;                                                      \
            for (int i = 0; i < 4; ++i)                                            \
                af[i]  = *(const bf16x8*)&As[mb + i * 16 + r][((k4 + quad) ^ (r & 7)) * 8]; \
            for (int j = 0; j < 4; ++j)                                            \
                bfr[j] = *(const bf16x8*)&Bs[nb + j * 16 + r][((k4 + quad) ^ (r & 7)) * 8]; \
            for (int i = 0; i < 4; ++i)                                            \
                for (int j = 0; j < 4; ++j)                                        \
                    acc[i][j] = __builtin_amdgcn_mfma_f32_16x16x32_bf16(af[i], bfr[j], acc[i][j], 0, 0, 0); \
        }                                                                          \
        __syncthreads();                                                           \
    }

// ---------------------------------------------------- out-projection GEMM
// C[M][N] = A[M][K] @ BT[N][K]^T + bias, fp32 out.
__global__ __launch_bounds__(256) void gemm_bt_kernel(const ushort_t* __restrict__ A,
                                                      const ushort_t* __restrict__ BT,
                                                      const float* __restrict__ bias,
                                                      float* __restrict__ C,
                                                      int M, int N, int K) {
    __shared__ ushort_t As[128][64];
    __shared__ ushort_t Bs[128][64];
    const int bm = blockIdx.x * 128, bn = blockIdx.y * 128;
    const int t = threadIdx.x;
    const int w = t >> 6, lane = t & 63, quad = lane >> 4, r = lane & 15;
    const int mb = (w >> 1) * 64, nb = (w & 1) * 64;
    f32x4 acc[4][4] = {};
    GEMM_MAIN_LOOP(A, BT, K)
    for (int i = 0; i < 4; ++i)
        for (int j = 0; j < 4; ++j)
            for (int reg = 0; reg < 4; ++reg) {
                int row = bm + mb + i * 16 + quad * 4 + reg;
                int col = bn + nb + j * 16 + r;
                C[(size_t)row * N + col] = acc[i][j][reg] + bias[col];
            }
}

// ------------------------------------- QKV GEMM + fused RMSNorm/rearrange
// N-tile 128 == one head group. g = blockIdx.y: 0..15 -> Q (rmsnorm*q_scale*SM),
// 16..19 -> K (rmsnorm*k_scale), 20..23 -> V plain (to Vn [nk][l][d]).
__global__ __launch_bounds__(256) void gemm_qkv_kernel(const ushort_t* __restrict__ A,
                                                       const ushort_t* __restrict__ BT,
                                                       const float* __restrict__ bias,
                                                       const float* __restrict__ q_scale,
                                                       const float* __restrict__ k_scale,
                                                       ushort_t* __restrict__ Q,
                                                       ushort_t* __restrict__ Kb,
                                                       ushort_t* __restrict__ Vn) {
    __shared__ ushort_t As[128][64];
    __shared__ ushort_t Bs[128][64];
    __shared__ float ssum[2][128];
    const int K = D_MODEL;
    const int bm = blockIdx.x * 128, bn = blockIdx.y * 128;
    const int t = threadIdx.x;
    const int w = t >> 6, lane = t & 63, quad = lane >> 4, r = lane & 15;
    const int mb = (w >> 1) * 64, nb = (w & 1) * 64;
    f32x4 acc[4][4] = {};
    GEMM_MAIN_LOOP(A, BT, K)

    const int g = blockIdx.y;
    float bj[4];
    for (int j = 0; j < 4; ++j) bj[j] = bias[bn + nb + j * 16 + r];
    for (int i = 0; i < 4; ++i)
        for (int j = 0; j < 4; ++j)
            for (int reg = 0; reg < 4; ++reg) acc[i][j][reg] += bj[j];

    const int n = bm >> 11, lb = bm & 2047;
    if (g < 20) {
        // row sums of squares over this block's 128 cols (2 waves share rows)
        for (int i = 0; i < 4; ++i)
            for (int reg = 0; reg < 4; ++reg) {
                float p = 0.f;
                for (int j = 0; j < 4; ++j) p += acc[i][j][reg] * acc[i][j][reg];
                p += __shfl_xor(p, 1); p += __shfl_xor(p, 2);
                p += __shfl_xor(p, 4); p += __shfl_xor(p, 8);
                if (r == 0) ssum[w & 1][mb + i * 16 + quad * 4 + reg] = p;
            }
        __syncthreads();
        const float* scp = (g < 16) ? q_scale : k_scale;
        const float smul = (g < 16) ? SM_SCALE : 1.0f;
        float scj[4];
        for (int j = 0; j < 4; ++j) scj[j] = scp[nb + j * 16 + r];
        ushort_t* dst = (g < 16) ? (Q  + (size_t)(n * 16 + g) * SEQ * HD)
                                 : (Kb + (size_t)(n * 4 + g - 16) * SEQ * HD);
        for (int i = 0; i < 4; ++i)
            for (int reg = 0; reg < 4; ++reg) {
                int rl = mb + i * 16 + quad * 4 + reg;
                float ss = ssum[0][rl] + ssum[1][rl];
                float iv = rsqrtf(ss * (1.0f / 128.0f) + 1e-6f) * smul;
                size_t lrow = lb + rl;
                for (int j = 0; j < 4; ++j) {
                    int d = nb + j * 16 + r;
                    dst[lrow * HD + d] = f2bf(acc[i][j][reg] * iv * scj[j]);
                }
            }
    } else {
        ushort_t* dst = Vn + (size_t)(n * 4 + g - 20) * SEQ * HD;
        for (int i = 0; i < 4; ++i)
            for (int reg = 0; reg < 4; ++reg) {
                size_t lrow = lb + mb + i * 16 + quad * 4 + reg;
                for (int j = 0; j < 4; ++j) {
                    int d = nb + j * 16 + r;
                    dst[lrow * HD + d] = f2bf(acc[i][j][reg]);
                }
            }
    }
}

// --------------------------------------------------- flash causal attention
// grid (8, 16, 4) = 512 blocks = 2/CU (LDS 48 KB). Block = 4 waves, each wave
// owns a 32-q-row strip (block tile 128 q-rows). Paired q-tiles {pid, 15-pid}:
// 34 tile-steps per block, perfectly balanced. Fixed-max softmax. LDS-traffic
// optimized: K/V frag reads shared across 2 row-strips; Q frags global->VGPR.
__global__ __launch_bounds__(256, 2) void attn_kernel(const ushort_t* __restrict__ Q,
                                                      const ushort_t* __restrict__ K,
                                                      const ushort_t* __restrict__ Vt,
                                                      ushort_t* __restrict__ Y) {
    const int pid = blockIdx.x, h = blockIdx.y, n = blockIdx.z;
    const int kvh = h >> 2;
    const ushort_t* Qp = Q  + (size_t)(n * N_HEADS + h) * SEQ * HD;
    const ushort_t* Kp = K  + (size_t)(n * N_KV + kvh) * SEQ * HD;
    const ushort_t* Vp = Vt + (size_t)(n * N_KV + kvh) * HD * SEQ;   // [d][l]

    __shared__ ushort_t Ks[64][128];    // 16 KB, chunk-swizzled
    __shared__ ushort_t Vts[128][64];   // 16 KB, chunk-swizzled ([d][key])
    __shared__ ushort_t Ps[128][64];    // 16 KB, quad-xor swizzled

    const int t = threadIdx.x, w = t >> 6, lane = t & 63, quad = lane >> 4, r = lane & 15;

    for (int rep = 0; rep < 2; ++rep) {
        const int qt = rep ? (15 - pid) : pid;
        const int q0 = qt * 128;

        // Q fragments straight from global (A-layout is contiguous 16B/lane)
        bf16x8 aq[2][4];
        for (int s = 0; s < 2; ++s)
            for (int kc = 0; kc < 4; ++kc)
                aq[s][kc] = *(const bf16x8*)&Qp[(size_t)(q0 + w * 32 + s * 16 + r) * HD + kc * 32 + quad * 8];

        f32x4 oacc[2][8] = {};
        float lsum[2][4] = {};
        const int nct = 2 * qt + 2;

        for (int ct = 0; ct < nct; ++ct) {
            __syncthreads();    // prior step's (or rep's) LDS reads complete
            for (int i = 0; i < 4; ++i) {
                int ci = (w * 4 + i) * 64 + lane;
                {   // K tile 64x128: 16 chunks/row
                    int row = ci >> 4, c = ci & 15, cg = c ^ (row & 7);
                    gload16(&Kp[(size_t)(ct * 64 + row) * HD + cg * 8], &Ks[0][0] + (w * 4 + i) * 512);
                }
                {   // Vt tile 128x64: 8 chunks/row
                    int row = ci >> 3, c = ci & 7, cg = c ^ (row & 7);
                    gload16(&Vp[(size_t)row * SEQ + ct * 64 + cg * 8], &Vts[0][0] + (w * 4 + i) * 512);
                }
            }
            __syncthreads();

            // S strips [2 x 16 x 64]: QK^T (scale folded into Q); bk shared by strips
            f32x4 sacc[2][4] = {};
            for (int kc = 0; kc < 4; ++kc)
                for (int jt = 0; jt < 4; ++jt) {
                    bf16x8 bk = *(const bf16x8*)&Ks[jt * 16 + r][((kc * 4 + quad) ^ (r & 7)) * 8];
                    sacc[0][jt] = __builtin_amdgcn_mfma_f32_16x16x32_bf16(aq[0][kc], bk, sacc[0][jt], 0, 0, 0);
                    sacc[1][jt] = __builtin_amdgcn_mfma_f32_16x16x32_bf16(aq[1][kc], bk, sacc[1][jt], 0, 0, 0);
                }

            // fixed-max softmax; P stored as truncated bf16 (high half)
            const bool diag = (ct >= 2 * qt);
            for (int s = 0; s < 2; ++s)
                for (int reg = 0; reg < 4; ++reg) {
                    int prow = w * 32 + s * 16 + quad * 4 + reg;
                    int qg = q0 + prow;
                    float rs = 0.f;
                    for (int jt = 0; jt < 4; ++jt) {
                        float sv = sacc[s][jt][reg];
                        if (diag && (ct * 64 + jt * 16 + r) > qg) sv = -1e30f;
                        float p = __expf(sv);
                        rs += p;
                        Ps[prow][(jt * 16 + r) ^ (quad << 4)] = (ushort_t)(__float_as_uint(p) >> 16);
                    }
                    lsum[s][reg] += rs;
                }

            // PV: O[2x16x128] += P @ V ; bv shared by strips; Ps rows wave-private
            for (int kk = 0; kk < 64; kk += 32) {
                bf16x8 pa[2];
                for (int s = 0; s < 2; ++s)
                    pa[s] = *(const bf16x8*)&Ps[w * 32 + s * 16 + r][(kk + quad * 8) ^ (((r >> 2) & 3) << 4)];
                for (int dt = 0; dt < 8; ++dt) {
                    bf16x8 bv = *(const bf16x8*)&Vts[dt * 16 + r][(((kk >> 3) + quad) ^ (r & 7)) * 8];
                    oacc[0][dt] = __builtin_amdgcn_mfma_f32_16x16x32_bf16(pa[0], bv, oacc[0][dt], 0, 0, 0);
                    oacc[1][dt] = __builtin_amdgcn_mfma_f32_16x16x32_bf16(pa[1], bv, oacc[1][dt], 0, 0, 0);
                }
            }
        }

        // epilogue: end-of-loop row-sum reduction, then Y
        for (int s = 0; s < 2; ++s)
            for (int reg = 0; reg < 4; ++reg) {
                float sv = lsum[s][reg];
                for (int m = 1; m < 16; m <<= 1) sv += __shfl_xor(sv, m);
                float invl = 1.0f / sv;
                int lrow = q0 + w * 32 + s * 16 + quad * 4 + reg;
                size_t base = ((size_t)(n * SEQ + lrow)) * D_MODEL + h * HD;
                for (int dt = 0; dt < 8; ++dt)
                    Y[base + dt * 16 + r] = f2bf(oacc[s][dt][reg] * invl);
            }
    }
}

// ------------------------------------------------------------------ launch
extern "C" void kernel_launch(void* const* d_in, const int* in_sizes, int n_in,
                              void* d_out, int out_size, void* d_ws, size_t ws_size,
                              hipStream_t stream) {
    const float* x       = (const float*)d_in[0];
    const float* Wqkv    = (const float*)d_in[1];
    const float* bqkv    = (const float*)d_in[2];
    const float* q_scale = (const float*)d_in[3];
    const float* k_scale = (const float*)d_in[4];
    const float* Wout    = (const float*)d_in[5];
    const float* bout    = (const float*)d_in[6];
    float* out = (float*)d_out;

    ushort_t* xb  = (ushort_t*)d_ws;                        // 8192*2048 (later: y)
    ushort_t* WT  = xb  + (size_t)MROWS * D_MODEL;          // 3072*2048 (later: WoutT)
    ushort_t* Qb  = WT  + (size_t)NQKV * D_MODEL;           // 4*16*2048*128
    ushort_t* Kb  = Qb  + (size_t)NB * N_HEADS * SEQ * HD;  // 4*4*2048*128
    ushort_t* Vnb = Kb  + (size_t)NB * N_KV * SEQ * HD;     // 4*4*2048*128
    ushort_t* Vtb = Vnb + (size_t)NB * N_KV * SEQ * HD;     // 4*4*128*2048

    conv_x_kernel<<<MROWS * D_MODEL / 1024, 256, 0, stream>>>(x, xb, MROWS * D_MODEL);
    conv_wt_kernel<<<dim3(NQKV / 32, D_MODEL / 32), dim3(32, 8), 0, stream>>>(Wqkv, WT, D_MODEL, NQKV);
    gemm_qkv_kernel<<<dim3(MROWS / 128, NQKV / 128), 256, 0, stream>>>(xb, WT, bqkv, q_scale, k_scale, Qb, Kb, Vnb);
    vt_kernel<<<dim3(SEQ / 64, HD / 64, NB * N_KV), 256, 0, stream>>>(Vnb, Vtb);
    conv_wt_kernel<<<dim3(D_MODEL / 32, D_MODEL / 32), dim3(32, 8), 0, stream>>>(Wout, WT, D_MODEL, D_MODEL);
    attn_kernel<<<dim3(8, N_HEADS, NB), 256, 0, stream>>>(Qb, Kb, Vtb, xb);
    gemm_bt_kernel<<<dim3(MROWS / 128, D_MODEL / 128), 256, 0, stream>>>(xb, WT, bout, out, MROWS, D_MODEL, D_MODEL);
}